// Round 8
// baseline (26160.040 us; speedup 1.0000x reference)
//
#include <hip/hip_runtime.h>

// PointerNetwork: B=2048, L=64, E=H=128, STEPS=126, out=(127,B,64) fp32.
// v9: 1024 threads/block (16 waves = exactly 4 waves/SIMD -> natural 128-VGPR
// budget), one batch per block, persistent over 126 steps.
// Register demand is SIZED TO FIT 128 VGPRs (r4-r6 lesson: 512-thr design
// needed ~220 regs, allocator pinned 128 and spilled weights to scratch ->
// 15 us/step):
//   - gates: 2 thr/row, k-half kh=t&1 (intra-wave shfl_xor(1) combine),
//     whh = 16 float4 = 64 VGPRs.
//   - qg/qp: 4 thr/row (quarter-k), qw = 8 float4 = 32 VGPRs,
//     shfl_xor(1)+(2) reduce. Threads <512: gWq, >=512: pWq.
//   ~96 persistent + ~30 transient = fits.
// tanh tables tegS/tepS in LDS [h][l]; raw e_g in egT[64][129] (pad -> the
// 148M bank conflicts from r4-6 column writes go away).
// tanh identity: tanh(q+e) = (Tq+Te)/(1+Tq*Te) with v_rcp.
// x@W_ih.T precomputed into workspace (XW).

#define B_ 2048
#define L_ 64
#define H_ 128
#define STEPS_ 126
#define NEGV -1000000000.0f

__device__ __forceinline__ float fast_rcp(float x) { return __builtin_amdgcn_rcpf(x); }
__device__ __forceinline__ float sigm(float x) { return 1.0f / (1.0f + __expf(-x)); }
__device__ __forceinline__ float dot4(float4 a, float4 b) {
  return a.x * b.x + a.y * b.y + a.z * b.z + a.w * b.w;
}

// ---------------- K1: XW = A[M,128] @ W[512,128]^T + (b1+b2) ----------------
__global__ __launch_bounds__(256) void xw_gemm(const float* __restrict__ A,
                                               const float* __restrict__ W,
                                               const float* __restrict__ b1,
                                               const float* __restrict__ b2,
                                               float* __restrict__ C) {
  __shared__ float As[64][36];
  __shared__ float Ws[64][36];
  const int t = threadIdx.x;
  const int tx = t & 15, ty = t >> 4;
  const long row0 = (long)blockIdx.x * 64;
  const int col0 = blockIdx.y * 64;
  float acc[4][4] = {};
  for (int k0 = 0; k0 < 128; k0 += 32) {
#pragma unroll
    for (int i = 0; i < 2; ++i) {
      int f4 = t * 2 + i;
      int r = f4 >> 3, c = (f4 & 7) * 4;
      *(float4*)&As[r][c] = *(const float4*)&A[(row0 + r) * 128 + k0 + c];
      *(float4*)&Ws[r][c] = *(const float4*)&W[(long)(col0 + r) * 128 + k0 + c];
    }
    __syncthreads();
#pragma unroll
    for (int kk = 0; kk < 32; kk += 4) {
      float4 a[4], w[4];
#pragma unroll
      for (int i = 0; i < 4; ++i) a[i] = *(float4*)&As[ty * 4 + i][kk];
#pragma unroll
      for (int j = 0; j < 4; ++j) w[j] = *(float4*)&Ws[tx * 4 + j][kk];
#pragma unroll
      for (int i = 0; i < 4; ++i)
#pragma unroll
        for (int j = 0; j < 4; ++j)
          acc[i][j] += dot4(a[i], w[j]);
    }
    __syncthreads();
  }
#pragma unroll
  for (int i = 0; i < 4; ++i) {
    long r = row0 + ty * 4 + i;
#pragma unroll
    for (int j = 0; j < 4; ++j) {
      int cc = col0 + tx * 4 + j;
      C[r * 512 + cc] = acc[i][j] + b1[cc] + b2[cc];
    }
  }
}

// ---------------- main persistent kernel: one block per batch ----------------
__global__ __launch_bounds__(1024) void ptrnet_main(
    const float* __restrict__ dec, const float* __restrict__ emb,
    const float* __restrict__ ctx, const float* __restrict__ h0,
    const float* __restrict__ c0, const float* __restrict__ W_ih,
    const float* __restrict__ W_hh, const float* __restrict__ b_ih,
    const float* __restrict__ b_hh, const float* __restrict__ gWq,
    const float* __restrict__ gbq, const float* __restrict__ gWref,
    const float* __restrict__ gbref, const float* __restrict__ gv,
    const float* __restrict__ pWq, const float* __restrict__ pbq,
    const float* __restrict__ pWref, const float* __restrict__ pbref,
    const float* __restrict__ pv, const float* __restrict__ XW,
    const float* __restrict__ XW0, float* __restrict__ out, int use_precomp) {
  const int b = blockIdx.x;
  const int t = threadIdx.x;
  const int lane = t & 63;
  const int wid = t >> 6;  // 0..15

  __shared__ float tegS[128][64];  // tanh(e_g), [h][l]
  __shared__ float tepS[128][64];  // tanh(e_p)
  __shared__ float egT[64][129];   // raw e_g, [l][h], padded (bank-safe col writes)
  __shared__ __align__(16) float hS[128];
  __shared__ float cS[128];
  __shared__ __align__(16) float glS[128];
  __shared__ __align__(16) float xS[128];
  __shared__ float gatesS[512];
  __shared__ __align__(16) float aG[128];
  __shared__ __align__(16) float gvaG[128];
  __shared__ __align__(16) float aP[128];
  __shared__ __align__(16) float pvaP[128];
  __shared__ __align__(16) float gvS[128];
  __shared__ __align__(16) float pvS[128];
  __shared__ float gbqS[128], pbqS[128];
  __shared__ float bS[512];
  __shared__ __align__(16) float wS[64];
  __shared__ float part2[16][64];
  __shared__ float red8[8][128];
  __shared__ int maskS[64];
  __shared__ int curS;

  // ---- setup ----
  if (t < 128) {
    hS[t] = h0[(long)b * 128 + t];
    cS[t] = c0[(long)b * 128 + t];
    gvS[t] = gv[t];
    pvS[t] = pv[t];
    gbqS[t] = gbq[t];
    pbqS[t] = pbq[t];
  }
  if (t < 512) bS[t] = b_ih[t] + b_hh[t];
  if (t < 64) {
    maskS[t] = 0;
    out[(long)b * 64 + t] = (t == 0) ? 1.0f : 0.0f;  // prob0 row
  }
  if (t == 0) curS = 0;

  // e_g / e_p: thread (l=lane, wid) computes 8 h-rows
  {
    const float4* crow4 = (const float4*)(ctx + ((long)lane * B_ + b) * 128);
#pragma unroll
    for (int k = 0; k < 8; ++k) {
      int h = wid * 8 + k;
      float eg = gbref[h], ep = pbref[h];
      const float4* wg4 = (const float4*)(gWref + (long)h * 128);
      const float4* wp4 = (const float4*)(pWref + (long)h * 128);
#pragma unroll
      for (int c = 0; c < 32; ++c) {
        float4 cv = crow4[c];
        eg += dot4(cv, wg4[c]);
        ep += dot4(cv, wp4[c]);
      }
      egT[lane][h] = eg;
      tegS[h][lane] = tanhf(eg);
      tepS[h][lane] = tanhf(ep);
    }
  }

  // loop-resident weights (sized for the 128-VGPR budget)
  const int r = t >> 1;    // gate row 0..511
  const int kh = t & 1;    // k-half
  float4 whh[16];
  {
    const float4* Whh4 = (const float4*)W_hh;
#pragma unroll
    for (int c = 0; c < 16; ++c) whh[c] = Whh4[(long)r * 32 + kh * 16 + c];
  }
  const int qj = (t & 511) >> 2;  // q row 0..127
  const int qk = t & 3;           // k-quarter
  float4 qw[8];
  {
    const float4* Q4 = (t < 512) ? (const float4*)gWq : (const float4*)pWq;
#pragma unroll
    for (int c = 0; c < 8; ++c) qw[c] = Q4[(long)qj * 32 + qk * 8 + c];
  }
  __syncthreads();

  const float4* hS4 = (const float4*)hS;
  const float4* glS4 = (const float4*)glS;
  const float4* xS4 = (const float4*)xS;
  float4* xS4w = (float4*)xS;

  for (int step = 0; step < STEPS_; ++step) {
    const int cur = curS;
    if (t == 0) {  // mask update with PREVIOUS chosen index
      maskS[cur] = 1;
      if (cur != 0) maskS[0] = 0;
    }

    // ---- (fallback only): stage x row ----
    if (!use_precomp) {
      if (t < 32)
        xS4w[t] = (step == 0) ? ((const float4*)(dec + (long)b * 128))[t]
                              : ((const float4*)(emb + ((long)cur * B_ + b) * 128))[t];
      __syncthreads();
    }

    // ---- gates: pair (t, t^1) owns row r; kh = k-half ----
    {
      float acc = 0.f;
#pragma unroll
      for (int c = 0; c < 16; ++c) acc += dot4(whh[c], hS4[kh * 16 + c]);
      if (!use_precomp) {
        const float4* wih4 = (const float4*)(W_ih + (long)r * 128);
#pragma unroll
        for (int c = 0; c < 16; ++c) acc += dot4(wih4[kh * 16 + c], xS4[kh * 16 + c]);
      }
      acc += __shfl_xor(acc, 1);
      if (kh == 0) {
        float xv;
        if (use_precomp) {
          const float* xw = (step == 0) ? (XW0 + (long)b * 512)
                                        : (XW + ((long)cur * B_ + b) * 512);
          xv = xw[r];
        } else {
          xv = bS[r];
        }
        gatesS[r] = acc + xv;
      }
    }
    __syncthreads();

    // ---- LSTM cell ----
    if (t < 128) {
      float gi = gatesS[t], gf = gatesS[t + 128];
      float gg = gatesS[t + 256], go = gatesS[t + 384];
      float cn = sigm(gf) * cS[t] + sigm(gi) * tanhf(gg);
      cS[t] = cn;
      hS[t] = sigm(go) * tanhf(cn);
    }
    __syncthreads();

    // ---- qg = h @ gWq^T + gbq (threads 0..511; 4 thr/row) ----
    if (t < 512) {
      float p = 0.f;
#pragma unroll
      for (int c = 0; c < 8; ++c) p += dot4(qw[c], hS4[qk * 8 + c]);
      p += __shfl_xor(p, 1);
      p += __shfl_xor(p, 2);
      if (qk == 0) {
        float a = tanhf(p + gbqS[qj]);
        aG[qj] = a;
        gvaG[qj] = gvS[qj] * a;
      }
    }
    __syncthreads();

    // ---- ug partials: thread (lane, wid) handles h = wid*8..+8 ----
    {
      const float4* a4 = (const float4*)aG;
      const float4* g4 = (const float4*)gvS;
      const float4* ga4 = (const float4*)gvaG;
      float sum = 0.f;
#pragma unroll
      for (int ch = 0; ch < 2; ++ch) {
        float4 av = a4[wid * 2 + ch];
        float4 gg4 = g4[wid * 2 + ch];
        float4 gav = ga4[wid * 2 + ch];
        const float* af = (const float*)&av;
        const float* gf = (const float*)&gg4;
        const float* gaf = (const float*)&gav;
#pragma unroll
        for (int k = 0; k < 4; ++k) {
          float te = tegS[wid * 8 + ch * 4 + k][lane];
          float den = fmaf(af[k], te, 1.0f);
          float n2 = fmaf(gf[k], te, gaf[k]);
          sum = fmaf(n2, fast_rcp(den), sum);
        }
      }
      part2[wid][lane] = sum;
    }
    __syncthreads();

    // ---- softmax over ug (wave 0) -> attention weights wS ----
    if (t < 64) {
      float u = 0.f;
#pragma unroll
      for (int i = 0; i < 16; ++i) u += part2[i][t];
      if (maskS[t]) u = NEGV;
      float m = u;
#pragma unroll
      for (int d = 32; d; d >>= 1) m = fmaxf(m, __shfl_xor(m, d));
      float e = __expf(u - m);
      float s = e;
#pragma unroll
      for (int d = 32; d; d >>= 1) s += __shfl_xor(s, d);
      wS[t] = e / s;
    }
    __syncthreads();

    // ---- g_l[h] = sum_l e_g[h,l]*w[l]; 8 l per thread ----
    {
      int h = t & 127, lh = t >> 7;  // lh 0..7
      float4 w0 = ((const float4*)wS)[lh * 2];
      float4 w1 = ((const float4*)wS)[lh * 2 + 1];
      const float* wf0 = (const float*)&w0;
      const float* wf1 = (const float*)&w1;
      float sum = 0.f;
#pragma unroll
      for (int q = 0; q < 4; ++q) sum = fmaf(egT[lh * 8 + q][h], wf0[q], sum);
#pragma unroll
      for (int q = 0; q < 4; ++q) sum = fmaf(egT[lh * 8 + 4 + q][h], wf1[q], sum);
      red8[lh][h] = sum;
    }
    __syncthreads();
    if (t < 128) {
      float s = 0.f;
#pragma unroll
      for (int i = 0; i < 8; ++i) s += red8[i][t];
      glS[t] = s;
    }
    __syncthreads();

    // ---- qp = g_l @ pWq^T + pbq (threads 512..1023; 4 thr/row) ----
    if (t >= 512) {
      float p = 0.f;
#pragma unroll
      for (int c = 0; c < 8; ++c) p += dot4(qw[c], glS4[qk * 8 + c]);
      p += __shfl_xor(p, 1);
      p += __shfl_xor(p, 2);
      if (qk == 0) {
        float a = tanhf(p + pbqS[qj]);
        aP[qj] = a;
        pvaP[qj] = pvS[qj] * a;
      }
    }
    __syncthreads();

    // ---- up partials ----
    {
      const float4* a4 = (const float4*)aP;
      const float4* p4 = (const float4*)pvS;
      const float4* pa4 = (const float4*)pvaP;
      float sum = 0.f;
#pragma unroll
      for (int ch = 0; ch < 2; ++ch) {
        float4 av = a4[wid * 2 + ch];
        float4 pp4 = p4[wid * 2 + ch];
        float4 pav = pa4[wid * 2 + ch];
        const float* af = (const float*)&av;
        const float* pf = (const float*)&pp4;
        const float* paf = (const float*)&pav;
#pragma unroll
        for (int k = 0; k < 4; ++k) {
          float te = tepS[wid * 8 + ch * 4 + k][lane];
          float den = fmaf(af[k], te, 1.0f);
          float n2 = fmaf(pf[k], te, paf[k]);
          sum = fmaf(n2, fast_rcp(den), sum);
        }
      }
      part2[wid][lane] = sum;
    }
    __syncthreads();

    // ---- final softmax + output + argmax (wave 0) ----
    if (t < 64) {
      float u = 0.f;
#pragma unroll
      for (int i = 0; i < 16; ++i) u += part2[i][t];
      u = 10.0f * tanhf(u);
      if (maskS[t]) u = NEGV;
      float m = u;
#pragma unroll
      for (int d = 32; d; d >>= 1) m = fmaxf(m, __shfl_xor(m, d));
      float e = __expf(u - m);
      float s = e;
#pragma unroll
      for (int d = 32; d; d >>= 1) s += __shfl_xor(s, d);
      float p = e / s;
      out[((long)(step + 1) * B_ + b) * 64 + t] = p;
      // argmax with first-index tie-break (matches numpy)
      float bv = p;
      int bi = t;
#pragma unroll
      for (int d = 32; d; d >>= 1) {
        float ov = __shfl_xor(bv, d);
        int oi = __shfl_xor(bi, d);
        if (ov > bv || (ov == bv && oi < bi)) { bv = ov; bi = oi; }
      }
      if (t == 0) curS = bi;
    }
    __syncthreads();
  }
}

extern "C" void kernel_launch(void* const* d_in, const int* in_sizes, int n_in,
                              void* d_out, int out_size, void* d_ws, size_t ws_size,
                              hipStream_t stream) {
  const float* dec = (const float*)d_in[0];
  const float* emb = (const float*)d_in[1];
  const float* ctx = (const float*)d_in[2];
  const float* h0 = (const float*)d_in[3];
  const float* c0 = (const float*)d_in[4];
  const float* Wih = (const float*)d_in[5];
  const float* Whh = (const float*)d_in[6];
  const float* bih = (const float*)d_in[7];
  const float* bhh = (const float*)d_in[8];
  const float* gWq = (const float*)d_in[9];
  const float* gbq = (const float*)d_in[10];
  const float* gWref = (const float*)d_in[11];
  const float* gbref = (const float*)d_in[12];
  const float* gv = (const float*)d_in[13];
  const float* pWq = (const float*)d_in[14];
  const float* pbq = (const float*)d_in[15];
  const float* pWref = (const float*)d_in[16];
  const float* pbref = (const float*)d_in[17];
  const float* pv = (const float*)d_in[18];
  float* out = (float*)d_out;

  const size_t xw_elems = (size_t)L_ * B_ * 512;
  const size_t need = (xw_elems + (size_t)B_ * 512) * sizeof(float);
  const int use_precomp = (ws_size >= need) ? 1 : 0;
  float* XW = (float*)d_ws;
  float* XW0 = XW + xw_elems;

  if (use_precomp) {
    dim3 g1((L_ * B_) / 64, 512 / 64);
    xw_gemm<<<g1, 256, 0, stream>>>(emb, Wih, bih, bhh, XW);
    dim3 g2(B_ / 64, 512 / 64);
    xw_gemm<<<g2, 256, 0, stream>>>(dec, Wih, bih, bhh, XW0);
  }
  ptrnet_main<<<dim3(B_), dim3(1024), 0, stream>>>(
      dec, emb, ctx, h0, c0, Wih, Whh, bih, bhh, gWq, gbq, gWref, gbref, gv,
      pWq, pbq, pWref, pbref, pv, XW, XW0, out, use_precomp);
}

// Round 9
// 19665.440 us; speedup vs baseline: 1.3303x; 1.3303x over previous
//
#include <hip/hip_runtime.h>

// PointerNetwork: B=2048, L=64, E=H=128, STEPS=126, out=(127,B,64) fp32.
// v11: 512 thr/block, 1 batch/block, persistent over 126 steps.
// LESSON (r4-r8): the allocator gives this kernel at most 128 VGPRs no matter
// what (launch_bounds/waves_per_eu ignored; 1024thr even got 64) -> any design
// needing >128 spills to scratch (r8: 28GB HBM spill traffic). So v11 SIZES
// register residency to ~105 regs: only gWq/pWq quarter-rows live in regs
// (qwg[8]+qwp[8] = 64 VGPRs). W_hh is STREAMED from L2 each step as a
// coalesced transposed GEMV (WT[k][t], lane-consecutive, 4 accumulators),
// ~256KB/step/CU over ~56 B/cyc/CU L2 BW ~= 4.6K cyc/step.
// egT padded [64][129]: r5/r8's 1.5e8/6.6e8 bank conflicts were its column
// writes (stride 512B = all lanes same bank).
// tanh tables tegS/tepS in LDS [h][l]; tanh(q+e) = (Tq+Te)/(1+Tq*Te), v_rcp.
// x@W_ih.T precomputed (XW); W_hh^T precomputed (WT) for coalesced streaming.

#define B_ 2048
#define L_ 64
#define H_ 128
#define STEPS_ 126
#define NEGV -1000000000.0f

__device__ __forceinline__ float fast_rcp(float x) { return __builtin_amdgcn_rcpf(x); }
__device__ __forceinline__ float sigm(float x) { return 1.0f / (1.0f + __expf(-x)); }
__device__ __forceinline__ float dot4(float4 a, float4 b) {
  return a.x * b.x + a.y * b.y + a.z * b.z + a.w * b.w;
}

// ---------------- K1: XW = A[M,128] @ W[512,128]^T + (b1+b2) ----------------
__global__ __launch_bounds__(256) void xw_gemm(const float* __restrict__ A,
                                               const float* __restrict__ W,
                                               const float* __restrict__ b1,
                                               const float* __restrict__ b2,
                                               float* __restrict__ C) {
  __shared__ float As[64][36];
  __shared__ float Ws[64][36];
  const int t = threadIdx.x;
  const int tx = t & 15, ty = t >> 4;
  const long row0 = (long)blockIdx.x * 64;
  const int col0 = blockIdx.y * 64;
  float acc[4][4] = {};
  for (int k0 = 0; k0 < 128; k0 += 32) {
#pragma unroll
    for (int i = 0; i < 2; ++i) {
      int f4 = t * 2 + i;
      int r = f4 >> 3, c = (f4 & 7) * 4;
      *(float4*)&As[r][c] = *(const float4*)&A[(row0 + r) * 128 + k0 + c];
      *(float4*)&Ws[r][c] = *(const float4*)&W[(long)(col0 + r) * 128 + k0 + c];
    }
    __syncthreads();
#pragma unroll
    for (int kk = 0; kk < 32; kk += 4) {
      float4 a[4], w[4];
#pragma unroll
      for (int i = 0; i < 4; ++i) a[i] = *(float4*)&As[ty * 4 + i][kk];
#pragma unroll
      for (int j = 0; j < 4; ++j) w[j] = *(float4*)&Ws[tx * 4 + j][kk];
#pragma unroll
      for (int i = 0; i < 4; ++i)
#pragma unroll
        for (int j = 0; j < 4; ++j)
          acc[i][j] += dot4(a[i], w[j]);
    }
    __syncthreads();
  }
#pragma unroll
  for (int i = 0; i < 4; ++i) {
    long r = row0 + ty * 4 + i;
#pragma unroll
    for (int j = 0; j < 4; ++j) {
      int cc = col0 + tx * 4 + j;
      C[r * 512 + cc] = acc[i][j] + b1[cc] + b2[cc];
    }
  }
}

// ---------------- K2: WT[k][j] = W_hh[j][k] (coalesced-read transpose) ------
__global__ __launch_bounds__(256) void whh_transpose(const float* __restrict__ W,
                                                     float* __restrict__ WT) {
  int idx = blockIdx.x * 256 + threadIdx.x;  // 0..65535
  int j = idx >> 7, k = idx & 127;
  WT[k * 512 + j] = W[j * 128 + k];
}

// ---------------- main persistent kernel: one block per batch ----------------
__global__ __launch_bounds__(512) void ptrnet_main(
    const float* __restrict__ dec, const float* __restrict__ emb,
    const float* __restrict__ ctx, const float* __restrict__ h0,
    const float* __restrict__ c0, const float* __restrict__ W_ih,
    const float* __restrict__ W_hh, const float* __restrict__ b_ih,
    const float* __restrict__ b_hh, const float* __restrict__ gWq,
    const float* __restrict__ gbq, const float* __restrict__ gWref,
    const float* __restrict__ gbref, const float* __restrict__ gv,
    const float* __restrict__ pWq, const float* __restrict__ pbq,
    const float* __restrict__ pWref, const float* __restrict__ pbref,
    const float* __restrict__ pv, const float* __restrict__ XW,
    const float* __restrict__ XW0, const float* __restrict__ WT,
    float* __restrict__ out, int use_precomp) {
  const int b = blockIdx.x;
  const int t = threadIdx.x;
  const int l = t & 63;   // attn column owned by this thread
  const int hb = t >> 6;  // 0..7: owns h in [hb*16, hb*16+16)

  __shared__ float tegS[128][64];  // tanh(e_g), [h][l]
  __shared__ float tepS[128][64];  // tanh(e_p)
  __shared__ float egT[64][129];   // raw e_g, [l][h], PADDED (bank-safe)
  __shared__ __align__(16) float hS[128];
  __shared__ float cS[128];
  __shared__ __align__(16) float glS[128];
  __shared__ __align__(16) float xS[128];
  __shared__ float gatesS[512];
  __shared__ __align__(16) float aG[128];
  __shared__ __align__(16) float gvaG[128];
  __shared__ __align__(16) float aP[128];
  __shared__ __align__(16) float pvaP[128];
  __shared__ __align__(16) float gvS[128];
  __shared__ __align__(16) float pvS[128];
  __shared__ float gbqS[128], pbqS[128];
  __shared__ float bS[512];
  __shared__ float wS[64];
  __shared__ float part[8][64];
  __shared__ float red4[4][128];
  __shared__ int maskS[64];
  __shared__ int curS;

  // ---- setup ----
  if (t < 128) {
    hS[t] = h0[(long)b * 128 + t];
    cS[t] = c0[(long)b * 128 + t];
    gvS[t] = gv[t];
    pvS[t] = pv[t];
    gbqS[t] = gbq[t];
    pbqS[t] = pbq[t];
  }
  bS[t] = b_ih[t] + b_hh[t];
  if (t < 64) {
    maskS[t] = 0;
    out[(long)b * 64 + t] = (t == 0) ? 1.0f : 0.0f;  // prob0 row
  }
  if (t == 0) curS = 0;

  // e_g / e_p: thread (l, hb) computes 16 h-rows
  {
    const float4* crow4 = (const float4*)(ctx + ((long)l * B_ + b) * 128);
    for (int k = 0; k < 16; ++k) {
      int h = hb * 16 + k;
      float eg = gbref[h], ep = pbref[h];
      const float4* wg4 = (const float4*)(gWref + (long)h * 128);
      const float4* wp4 = (const float4*)(pWref + (long)h * 128);
#pragma unroll
      for (int c = 0; c < 32; ++c) {
        float4 cv = crow4[c];
        eg += dot4(cv, wg4[c]);
        ep += dot4(cv, wp4[c]);
      }
      egT[l][h] = eg;
      tegS[h][l] = tanhf(eg);
      tepS[h][l] = tanhf(ep);
    }
  }

  // loop-resident attention-query weights (quarter-rows): 64 VGPRs total.
  const int qj = t >> 2;  // q row 0..127
  const int qk = t & 3;   // k-quarter
  float4 qwg[8], qwp[8];
  {
    const float4* G4 = (const float4*)gWq;
    const float4* P4 = (const float4*)pWq;
#pragma unroll
    for (int c = 0; c < 8; ++c) {
      qwg[c] = G4[(long)qj * 32 + qk * 8 + c];
      qwp[c] = P4[(long)qj * 32 + qk * 8 + c];
    }
  }
  __syncthreads();

  const float4* hS4 = (const float4*)hS;
  const float4* glS4 = (const float4*)glS;
  const float4* xS4 = (const float4*)xS;
  float4* xS4w = (float4*)xS;

  for (int step = 0; step < STEPS_; ++step) {
    const int cur = curS;
    if (t == 0) {  // mask update with PREVIOUS chosen index
      maskS[cur] = 1;
      if (cur != 0) maskS[0] = 0;
    }

    // ---- gates: thread t owns row t; W_hh streamed from L2 ----
    if (use_precomp) {
      const float* xw = (step == 0) ? (XW0 + (long)b * 512)
                                    : (XW + ((long)cur * B_ + b) * 512);
      float xv = xw[t];  // issue early, independent of the WT stream
      float a0 = 0.f, a1 = 0.f, a2 = 0.f, a3 = 0.f;
#pragma unroll 8
      for (int k = 0; k < 128; k += 4) {
        a0 = fmaf(WT[(k + 0) * 512 + t], hS[k + 0], a0);
        a1 = fmaf(WT[(k + 1) * 512 + t], hS[k + 1], a1);
        a2 = fmaf(WT[(k + 2) * 512 + t], hS[k + 2], a2);
        a3 = fmaf(WT[(k + 3) * 512 + t], hS[k + 3], a3);
      }
      gatesS[t] = (a0 + a1) + (a2 + a3) + xv;
    } else {
      // fallback: stage x, stream W_ih + W_hh row-major
      if (t < 32)
        xS4w[t] = (step == 0) ? ((const float4*)(dec + (long)b * 128))[t]
                              : ((const float4*)(emb + ((long)cur * B_ + b) * 128))[t];
      __syncthreads();
      float acc = bS[t];
      const float4* wih4 = (const float4*)(W_ih + (long)t * 128);
      const float4* whh4 = (const float4*)(W_hh + (long)t * 128);
#pragma unroll
      for (int c = 0; c < 32; ++c) {
        acc += dot4(wih4[c], xS4[c]);
        acc += dot4(whh4[c], hS4[c]);
      }
      gatesS[t] = acc;
    }
    __syncthreads();

    // ---- LSTM cell ----
    if (t < 128) {
      float gi = gatesS[t], gf = gatesS[t + 128];
      float gg = gatesS[t + 256], go = gatesS[t + 384];
      float cn = sigm(gf) * cS[t] + sigm(gi) * tanhf(gg);
      cS[t] = cn;
      hS[t] = sigm(go) * tanhf(cn);
    }
    __syncthreads();

    // ---- qg = h @ gWq^T + gbq (4 thr/row, quarter-k in regs) ----
    {
      float p = 0.f;
#pragma unroll
      for (int c = 0; c < 8; ++c) p += dot4(qwg[c], hS4[qk * 8 + c]);
      p += __shfl_xor(p, 1);
      p += __shfl_xor(p, 2);
      if (qk == 0) {
        float a = tanhf(p + gbqS[qj]);
        aG[qj] = a;
        gvaG[qj] = gvS[qj] * a;
      }
    }
    __syncthreads();

    // ---- ug partials: sum_h gv*(Tq+Te)/(1+Tq*Te), 16 h per thread ----
    {
      const float4* a4 = (const float4*)aG;
      const float4* g4 = (const float4*)gvS;
      const float4* ga4 = (const float4*)gvaG;
      float4 av[4], gv4[4], gav[4];
#pragma unroll
      for (int i = 0; i < 4; ++i) {
        av[i] = a4[hb * 4 + i];
        gv4[i] = g4[hb * 4 + i];
        gav[i] = ga4[hb * 4 + i];
      }
      const float* af = (const float*)av;
      const float* gf = (const float*)gv4;
      const float* gaf = (const float*)gav;
      float sum = 0.f;
#pragma unroll
      for (int k = 0; k < 16; ++k) {
        float te = tegS[hb * 16 + k][l];
        float den = fmaf(af[k], te, 1.0f);
        float n2 = fmaf(gf[k], te, gaf[k]);
        sum = fmaf(n2, fast_rcp(den), sum);
      }
      part[hb][l] = sum;
    }
    __syncthreads();

    // ---- softmax over ug (wave 0) -> attention weights wS ----
    if (t < 64) {
      float u = part[0][l] + part[1][l] + part[2][l] + part[3][l] +
                part[4][l] + part[5][l] + part[6][l] + part[7][l];
      if (maskS[l]) u = NEGV;
      float m = u;
#pragma unroll
      for (int d = 32; d; d >>= 1) m = fmaxf(m, __shfl_xor(m, d));
      float e = __expf(u - m);
      float s = e;
#pragma unroll
      for (int d = 32; d; d >>= 1) s += __shfl_xor(s, d);
      wS[l] = e / s;
    }
    __syncthreads();

    // ---- g_l[h] = sum_l e_g[h,l]*w[l] ----
    {
      int h = t & 127, lh = t >> 7;
      float sum = 0.f;
#pragma unroll
      for (int q = 0; q < 16; ++q) {
        int l2 = lh * 16 + q;
        sum = fmaf(egT[l2][h], wS[l2], sum);
      }
      red4[lh][h] = sum;
    }
    __syncthreads();
    if (t < 128) glS[t] = red4[0][t] + red4[1][t] + red4[2][t] + red4[3][t];
    __syncthreads();

    // ---- qp = g_l @ pWq^T + pbq (4 thr/row, quarter-k in regs) ----
    {
      float p = 0.f;
#pragma unroll
      for (int c = 0; c < 8; ++c) p += dot4(qwp[c], glS4[qk * 8 + c]);
      p += __shfl_xor(p, 1);
      p += __shfl_xor(p, 2);
      if (qk == 0) {
        float a = tanhf(p + pbqS[qj]);
        aP[qj] = a;
        pvaP[qj] = pvS[qj] * a;
      }
    }
    __syncthreads();

    // ---- up partials ----
    {
      const float4* a4 = (const float4*)aP;
      const float4* p4 = (const float4*)pvS;
      const float4* pa4 = (const float4*)pvaP;
      float4 av[4], pv4[4], pav[4];
#pragma unroll
      for (int i = 0; i < 4; ++i) {
        av[i] = a4[hb * 4 + i];
        pv4[i] = p4[hb * 4 + i];
        pav[i] = pa4[hb * 4 + i];
      }
      const float* af = (const float*)av;
      const float* pf = (const float*)pv4;
      const float* paf = (const float*)pav;
      float sum = 0.f;
#pragma unroll
      for (int k = 0; k < 16; ++k) {
        float te = tepS[hb * 16 + k][l];
        float den = fmaf(af[k], te, 1.0f);
        float n2 = fmaf(pf[k], te, paf[k]);
        sum = fmaf(n2, fast_rcp(den), sum);
      }
      part[hb][l] = sum;
    }
    __syncthreads();

    // ---- final softmax + output + argmax (wave 0) ----
    if (t < 64) {
      float u = part[0][l] + part[1][l] + part[2][l] + part[3][l] +
                part[4][l] + part[5][l] + part[6][l] + part[7][l];
      u = 10.0f * tanhf(u);
      if (maskS[l]) u = NEGV;
      float m = u;
#pragma unroll
      for (int d = 32; d; d >>= 1) m = fmaxf(m, __shfl_xor(m, d));
      float e = __expf(u - m);
      float s = e;
#pragma unroll
      for (int d = 32; d; d >>= 1) s += __shfl_xor(s, d);
      float p = e / s;
      out[((long)(step + 1) * B_ + b) * 64 + l] = p;
      // argmax with first-index tie-break (matches numpy)
      float bv = p;
      int bi = l;
#pragma unroll
      for (int d = 32; d; d >>= 1) {
        float ov = __shfl_xor(bv, d);
        int oi = __shfl_xor(bi, d);
        if (ov > bv || (ov == bv && oi < bi)) { bv = ov; bi = oi; }
      }
      if (t == 0) curS = bi;
    }
    __syncthreads();
  }
}

extern "C" void kernel_launch(void* const* d_in, const int* in_sizes, int n_in,
                              void* d_out, int out_size, void* d_ws, size_t ws_size,
                              hipStream_t stream) {
  const float* dec = (const float*)d_in[0];
  const float* emb = (const float*)d_in[1];
  const float* ctx = (const float*)d_in[2];
  const float* h0 = (const float*)d_in[3];
  const float* c0 = (const float*)d_in[4];
  const float* Wih = (const float*)d_in[5];
  const float* Whh = (const float*)d_in[6];
  const float* bih = (const float*)d_in[7];
  const float* bhh = (const float*)d_in[8];
  const float* gWq = (const float*)d_in[9];
  const float* gbq = (const float*)d_in[10];
  const float* gWref = (const float*)d_in[11];
  const float* gbref = (const float*)d_in[12];
  const float* gv = (const float*)d_in[13];
  const float* pWq = (const float*)d_in[14];
  const float* pbq = (const float*)d_in[15];
  const float* pWref = (const float*)d_in[16];
  const float* pbref = (const float*)d_in[17];
  const float* pv = (const float*)d_in[18];
  float* out = (float*)d_out;

  const size_t xw_elems = (size_t)L_ * B_ * 512;
  const size_t x0_elems = (size_t)B_ * 512;
  const size_t wt_elems = (size_t)512 * 128;
  const size_t need = (xw_elems + x0_elems + wt_elems) * sizeof(float);
  const int use_precomp = (ws_size >= need) ? 1 : 0;
  float* XW = (float*)d_ws;
  float* XW0 = XW + xw_elems;
  float* WT = XW0 + x0_elems;

  if (use_precomp) {
    dim3 g1((L_ * B_) / 64, 512 / 64);
    xw_gemm<<<g1, 256, 0, stream>>>(emb, Wih, bih, bhh, XW);
    dim3 g2(B_ / 64, 512 / 64);
    xw_gemm<<<g2, 256, 0, stream>>>(dec, Wih, bih, bhh, XW0);
    whh_transpose<<<256, 256, 0, stream>>>(Whh, WT);
  }
  ptrnet_main<<<dim3(B_), dim3(512), 0, stream>>>(
      dec, emb, ctx, h0, c0, Wih, Whh, bih, bhh, gWq, gbq, gWref, gbref, gv,
      pWq, pbq, pWref, pbref, pv, XW, XW0, WT, out, use_precomp);
}